// Round 15
// baseline (201.278 us; speedup 1.0000x reference)
//
#include <hip/hip_runtime.h>

#define SEQ     8192
#define DM      1024
#define NB      256         // k2 blocks (1 per CU), fully independent
#define CH      32          // own timesteps per block
#define HALO    32          // lam<=0.55 -> 0.55^32 ~ 4e-9 boundary error (<< fp32 noise)
#define W       64          // HALO + CH
#define NT      512         // k2: 8 waves/CU (R7 proven config)
#define MAXITERS 20

__device__ __forceinline__ float sigmoidf(float x) {
    return 1.0f / (1.0f + __expf(-x));
}
__device__ __forceinline__ float tanh_fast(float x) {
    const float e = __expf(2.0f * x);
    return 1.0f - 2.0f / (e + 1.0f);
}

// ---------------- Kernel 1: embedding gather + iteration-invariant x-projections ----------------
// 1024 blocks x 8 tokens. Thread = (rows rgrp*4..+3, tokens 2*tpair..+1, k-quarter kq):
// per iter 4 weight b128 + ONLY 2 LDS b128 -> 16 FMA (LDS insts/lane 512 -> 128 vs old k1).
__global__ __launch_bounds__(256) void k1_embed_proj(
    const int* __restrict__ tokens, const float* __restrict__ emb,
    const float* __restrict__ Wf,  const float* __restrict__ bf,
    const float* __restrict__ Wf2, const float* __restrict__ bf2,
    const float* __restrict__ Wlam,const float* __restrict__ blam,
    const float* __restrict__ Wu,  const float* __restrict__ bu,
    float* __restrict__ xlam, float* __restrict__ xu,
    float* __restrict__ xf,   float* __restrict__ xf2)
{
    __shared__ float4 xs4[8 * 256];              // 32 KB
    const int tid = threadIdx.x;
    const int tokbase = blockIdx.x * 8;

    for (int j = tid; j < 8 * 256; j += 256) {   // stage 8 token rows, coalesced
        const int tok = j >> 8, q = j & 255;
        const int row = tokens[tokbase + tok];
        const int qs = q ^ ((tok & 3) << 1) ^ ((q >> 6) & 3);   // token+kq bank spread
        xs4[tok * 256 + qs] =
            *reinterpret_cast<const float4*>(emb + (size_t)row * DM + q * 4);
    }
    __syncthreads();

    const int kq    = tid & 3;                   // k-quarter
    const int tpair = (tid >> 2) & 3;            // token pair -> tokens 2*tpair, 2*tpair+1
    const int rgrp  = tid >> 4;                  // 0..15 -> rows rgrp*4 .. +3
    const int arr   = rgrp >> 2;                 // all 4 rows in the same array
    const int c0    = (rgrp & 3) * 4;            // base channel

    const float* wb; const float* bv; float* dst; int wstr, woff;
    if (arr == 0)      { wb = Wlam; wstr = 1056; woff = 32; bv = blam; dst = xlam; }
    else if (arr == 1) { wb = Wu;   wstr = 1056; woff = 32; bv = bu;   dst = xu;   }
    else if (arr == 2) { wb = Wf;   wstr = 1040; woff = 16; bv = bf;   dst = xf;   }
    else               { wb = Wf2;  wstr = 1040; woff = 16; bv = bf2;  dst = xf2;  }

    const float4* wr[4];
    #pragma unroll
    for (int rr = 0; rr < 4; ++rr)
        wr[rr] = reinterpret_cast<const float4*>(wb + (size_t)(c0 + rr) * wstr + woff) + kq * 64;

    float2 a2[4][2];
    #pragma unroll
    for (int rr = 0; rr < 4; ++rr)
        #pragma unroll
        for (int tt = 0; tt < 2; ++tt) a2[rr][tt] = make_float2(0.f, 0.f);

    const int t0 = tpair * 2;
    #pragma unroll 4
    for (int i = 0; i < 64; ++i) {
        const int q = kq * 64 + i;
        float4 w4[4];
        #pragma unroll
        for (int rr = 0; rr < 4; ++rr) w4[rr] = wr[rr][i];
        float4 x4[2];
        #pragma unroll
        for (int tt = 0; tt < 2; ++tt) {
            const int tok = t0 + tt;
            const int gs = q ^ ((tok & 3) << 1) ^ ((q >> 6) & 3);
            x4[tt] = xs4[tok * 256 + gs];
        }
        #pragma unroll
        for (int rr = 0; rr < 4; ++rr)
            #pragma unroll
            for (int tt = 0; tt < 2; ++tt) {
                a2[rr][tt].x += w4[rr].x * x4[tt].x + w4[rr].z * x4[tt].z;
                a2[rr][tt].y += w4[rr].y * x4[tt].y + w4[rr].w * x4[tt].w;
            }
    }

    #pragma unroll
    for (int rr = 0; rr < 4; ++rr)
        #pragma unroll
        for (int tt = 0; tt < 2; ++tt) {
            float acc = a2[rr][tt].x + a2[rr][tt].y;
            acc += __shfl_xor(acc, 1);           // reduce over kq (lane bits 0..1)
            acc += __shfl_xor(acc, 2);
            if (kq == 0)
                dst[(size_t)(tokbase + t0 + tt) * 16 + (c0 + rr)] = acc + bv[c0 + rr];
        }
}

// ---------------- Kernel 2: halo-local fixed-point loop (R7 proven: 87 us, 128 VGPR) ----------------
// Thread (tq = tid&31, c = tid>>5). Phase A in regs -> TWO sequential convergent Kogge-Stone
// scans in natural lane order (times 0..31, then 32..63 seeded by the lane-31 carry) ->
// h to LDS -> Phase F. z stored (u_c, v_c)-interleaved + float4-granule XOR swizzle.
__global__ __launch_bounds__(NT, 2) void k2_fixed_point(
    const float* __restrict__ Wf,  const float* __restrict__ Wf2,
    const float* __restrict__ Wlam,const float* __restrict__ Wu,
    const float* __restrict__ xf,  const float* __restrict__ xf2,
    const float* __restrict__ xlam,const float* __restrict__ xu,
    const float* __restrict__ Wout,const float* __restrict__ bout,
    float* __restrict__ out)
{
    __shared__ float zsf[W * 32];               // z, (u,v)-interleaved, granule-swizzled
    __shared__ float hhT[16][W + 2];            // [c][t], stride 66
    __shared__ float zhs[CH][48];

    const int tid = threadIdx.x;
    const int b = blockIdx.x;
    const int s0 = (b - 1) * CH;                // global t of local 0
    const int tq = tid & 31;                    // lane-in-halfwave = local time (mod 32)
    const int c  = tid >> 5;                    // channel 0..15

    for (int i = tid; i < W * 32; i += NT) zsf[i] = 0.0f;

    // ---- weights, interleaved for packed-f32 FMA ----
    float2 wlu[32];
    #pragma unroll
    for (int s = 0; s < 32; ++s) {
        const int oj = (s & 1) ? 16 + (s >> 1) : (s >> 1);
        wlu[s].x = Wlam[(size_t)c * 1056 + oj];
        wlu[s].y = Wu  [(size_t)c * 1056 + oj];
    }
    float2 wfs[16];
    #pragma unroll
    for (int j = 0; j < 16; ++j) {
        wfs[j].x = Wf [(size_t)c * 1040 + j];
        wfs[j].y = Wf2[(size_t)c * 1040 + j];
    }

    // ---- iteration-invariant x-projections (times tq, tq+32) ----
    float xl[2], xu_[2], xf_[2], x2_[2];
    bool act[2];
    #pragma unroll
    for (int k = 0; k < 2; ++k) {
        const int gt = s0 + tq + 32 * k;
        act[k] = (gt >= 0);
        const size_t gi = (size_t)(gt < 0 ? 0 : gt) * 16 + c;
        xl[k] = xlam[gi]; xu_[k] = xu[gi]; xf_[k] = xf[gi]; x2_[k] = xf2[gi];
    }
    __syncthreads();

    for (int r = 1; r <= MAXITERS + 1; ++r) {
        // ---- Phase A: (lam,u) in registers, packed accumulate ----
        float ae[2], be[2];
        #pragma unroll
        for (int k = 0; k < 2; ++k) {
            const int tl = tq + 32 * k;
            const int sw = tl & 7;
            float2 acc = make_float2(xl[k], xu_[k]);
            #pragma unroll
            for (int g = 0; g < 8; ++g) {
                const float4 z4 = *reinterpret_cast<const float4*>(
                    &zsf[tl * 32 + ((g ^ sw) << 2)]);
                acc.x += z4.x * wlu[4*g+0].x;  acc.y += z4.x * wlu[4*g+0].y;
                acc.x += z4.y * wlu[4*g+1].x;  acc.y += z4.y * wlu[4*g+1].y;
                acc.x += z4.z * wlu[4*g+2].x;  acc.y += z4.z * wlu[4*g+2].y;
                acc.x += z4.w * wlu[4*g+3].x;  acc.y += z4.w * wlu[4*g+3].y;
            }
            ae[k] = act[k] ? sigmoidf(acc.x) : 0.0f;
            be[k] = act[k] ? acc.y : 0.0f;
        }

        // ---- stage 1: Kogge-Stone over times 0..31 (lane = time, convergent) ----
        float A = ae[0], B = be[0];
        #pragma unroll
        for (int d = 1; d < 32; d <<= 1) {
            float pA = __shfl_up(A, d, 32);
            float pB = __shfl_up(B, d, 32);
            pA = (tq >= d) ? pA : 1.0f;
            pB = (tq >= d) ? pB : 0.0f;
            B = A * pB + B;
            A = A * pA;
        }
        const float h0v = B;                     // h at local time tq (h_{-1} = 0)
        const float carry = __shfl(B, 31, 32);   // h at local time 31

        // ---- stage 2: Kogge-Stone over times 32..63, seeded by carry ----
        float A1 = ae[1], B1 = be[1];
        #pragma unroll
        for (int d = 1; d < 32; d <<= 1) {
            float pA = __shfl_up(A1, d, 32);
            float pB = __shfl_up(B1, d, 32);
            pA = (tq >= d) ? pA : 1.0f;
            pB = (tq >= d) ? pB : 0.0f;
            B1 = A1 * pB + B1;
            A1 = A1 * pA;
        }
        const float h1v = A1 * carry + B1;       // h at local time tq+32

        hhT[c][tq]      = h0v;
        hhT[c][tq + 32] = h1v;
        __syncthreads();                         // BARRIER 1: h ready, A-reads of zsf done

        if (r == MAXITERS + 1) {
            // ---- fused epilogue: out = [z, h] @ Wout.T + bout ----
            for (int i = tid; i < CH * 48; i += NT) {
                const int tt = i / 48, j = i - tt * 48;
                const int tl = HALO + tt;
                float v;
                if (j < 32) {
                    const int s = (j < 16) ? 2 * j : 2 * (j - 16) + 1;
                    v = zsf[tl * 32 + ((((s >> 2) ^ (tl & 7)) << 2) | (s & 3))];
                } else {
                    v = hhT[j - 32][tl];
                }
                zhs[tt][j] = v;
            }
            __syncthreads();
            #pragma unroll
            for (int q = 0; q < 2; ++q) {
                const int col = q * NT + tid;
                const float* wp = Wout + (size_t)col * 48;
                float4 wq[12];
                #pragma unroll
                for (int j = 0; j < 12; ++j)
                    wq[j] = *reinterpret_cast<const float4*>(wp + j * 4);
                const float bz = bout[col];
                for (int tt = 0; tt < CH; ++tt) {
                    float a = bz;
                    #pragma unroll
                    for (int j = 0; j < 12; ++j) {
                        const float4 z4 = *reinterpret_cast<const float4*>(&zhs[tt][j * 4]);
                        a += wq[j].x * z4.x + wq[j].y * z4.y
                           + wq[j].z * z4.z + wq[j].w * z4.w;
                    }
                    out[(size_t)(b * CH + tt) * 1024 + col] = a;
                }
            }
            break;
        }

        // ---- Phase F: f_theta ODE step (packed alpha/sigma, b64 z access) ----
        #pragma unroll
        for (int k = 0; k < 2; ++k) {
            const int tl = tq + 32 * k;
            const int tp = (tl == 0) ? 0 : tl - 1;
            float2 as2 = make_float2(xf_[k], x2_[k]);
            #pragma unroll
            for (int j = 0; j < 16; ++j) {
                const float hp = hhT[j][tp];
                as2.x += hp * wfs[j].x;
                as2.y += hp * wfs[j].y;
            }
            if (tl == 0) as2 = make_float2(xf_[k], x2_[k]);   // h_prev = 0 at block start
            const float al_ = sigmoidf(as2.x);
            const float sg  = sigmoidf(as2.y);

            const int sw = tl & 7;
            const int pos = tl * 32 + ((((c >> 1) ^ sw) << 2) | ((2 * c) & 3));
            float2 uv = *reinterpret_cast<const float2*>(&zsf[pos]);
            const float th = tanh_fast(30.0f * (uv.y - uv.x));
            const float du = 0.001f * ( 1.0f - al_ * __expf(15.6f * uv.y) * (1.0f - 0.26f * (0.3f - uv.x)) + sg * th);
            const float dv = 0.001f * (-1.0f + al_ * __expf(15.6f * uv.x) * (1.0f + 0.26f * (0.3f - uv.y)) + sg * th);
            if (act[k]) {
                uv.x += du; uv.y += dv;
                *reinterpret_cast<float2*>(&zsf[pos]) = uv;
            }
        }
        __syncthreads();                         // BARRIER 2: zsf settled for next round
    }
}

extern "C" void kernel_launch(void* const* d_in, const int* in_sizes, int n_in,
                              void* d_out, int out_size, void* d_ws, size_t ws_size,
                              hipStream_t stream) {
    (void)in_sizes; (void)n_in; (void)out_size; (void)ws_size;
    const int*   tokens = (const int*)  d_in[0];
    const float* emb    = (const float*)d_in[1];
    const float* Wf     = (const float*)d_in[2];
    const float* bf     = (const float*)d_in[3];
    const float* Wf2    = (const float*)d_in[4];
    const float* bf2    = (const float*)d_in[5];
    const float* Wlam   = (const float*)d_in[6];
    const float* blam   = (const float*)d_in[7];
    const float* Wu     = (const float*)d_in[8];
    const float* bu     = (const float*)d_in[9];
    const float* Wout   = (const float*)d_in[10];
    const float* bout   = (const float*)d_in[11];

    float* ws   = (float*)d_ws;
    float* xlam = ws;                       // 131072 f
    float* xu   = ws + 131072;
    float* xf   = ws + 262144;
    float* xf2  = ws + 393216;

    k1_embed_proj<<<SEQ / 8, 256, 0, stream>>>(tokens, emb, Wf, bf, Wf2, bf2,
                                               Wlam, blam, Wu, bu,
                                               xlam, xu, xf, xf2);

    k2_fixed_point<<<NB, NT, 0, stream>>>(Wf, Wf2, Wlam, Wu,
                                          xf, xf2, xlam, xu,
                                          Wout, bout, (float*)d_out);
}